// Round 7
// baseline (311.187 us; speedup 1.0000x reference)
//
#include <hip/hip_runtime.h>
#include <hip/hip_bf16.h>

// B=2, S=2048, D=1024, H=16, DH=64. fp32 in/out; bf16 MFMA internals.
#define S_LEN   2048
#define D_MODEL 1024
#define N_HEADS 16
#define D_HEAD  64
#define HEAD_ELEMS (2048ull * 64ull)          // elements per (b,h) plane
#define MAT_ELEMS  (4096ull * 1024ull)        // one projected matrix (Q/K/V)
#define W_ELEMS    (1024ull * 1024ull)        // one weight matrix

typedef __attribute__((ext_vector_type(8))) short short8_t;   // 8 bf16
typedef __attribute__((ext_vector_type(4))) short short4_t;   // 4 bf16
typedef __attribute__((ext_vector_type(4))) float f32x4;      // MFMA C/D frag

__device__ __forceinline__ short f2bf(float f) {
    __hip_bfloat16 h = __float2bfloat16(f);
    union { __hip_bfloat16 h; short s; } cv;
    cv.h = h;
    return cv.s;
}

// v_mfma_f32_16x16x16_bf16 via inline asm (ISA §10: D, A, B, C; A/B = 2 VGPR,
// C/D = 4 VGPR; gfx950 unified file allows v[] operands).
__device__ __forceinline__ f32x4 mfma16_bf16(short4_t a, short4_t b, f32x4 c) {
    f32x4 d;
    asm("v_mfma_f32_16x16x16_bf16 %0, %1, %2, %3"
        : "=v"(d) : "v"(a), "v"(b), "0"(c));
    return d;
}

// global_load_lds width=16: LDS dest = wave-uniform base + lane*16
#define GLD_LDS16(gptr, lptr) \
    __builtin_amdgcn_global_load_lds( \
        (const __attribute__((address_space(1))) unsigned int*)(gptr), \
        (__attribute__((address_space(3))) unsigned int*)(lptr), 16, 0, 0)

// ---------------------------------------------------------------------------
// Kernel 0a: convert x fp32 -> bf16.
// ---------------------------------------------------------------------------
__global__ __launch_bounds__(256) void convert_x_kernel(
    const float* __restrict__ x, short* __restrict__ xb)
{
    const int i = (blockIdx.x * 256 + threadIdx.x) * 8;
    const float4 v0 = *(const float4*)(x + i);
    const float4 v1 = *(const float4*)(x + i + 4);
    short8_t u;
    u[0] = f2bf(v0.x); u[1] = f2bf(v0.y); u[2] = f2bf(v0.z); u[3] = f2bf(v0.w);
    u[4] = f2bf(v1.x); u[5] = f2bf(v1.y); u[6] = f2bf(v1.z); u[7] = f2bf(v1.w);
    *(short8_t*)(xb + i) = u;
}

// ---------------------------------------------------------------------------
// Kernel 0b: convert + transpose W fp32[k][n] -> bf16 Wt[n][k].
// ---------------------------------------------------------------------------
__global__ __launch_bounds__(256) void transpose_w_kernel(
    const float* __restrict__ Wq, const float* __restrict__ Wk,
    const float* __restrict__ Wv, short* __restrict__ wt)
{
    const int k0 = blockIdx.x * 64;
    const int n0 = blockIdx.y * 64;
    const int which = blockIdx.z;
    const float* W = (which == 0) ? Wq : (which == 1) ? Wk : Wv;
    short* out = wt + (size_t)which * W_ELEMS;

    __shared__ float Ts[64][68];   // [n_local][k_local]
    const int t = threadIdx.x;
    {
        const int c4 = (t & 15) * 4;
#pragma unroll
        for (int i = 0; i < 4; ++i) {
            const int r = (t >> 4) + i * 16;
            const float4 v = *(const float4*)(W + (size_t)(k0 + r) * D_MODEL + n0 + c4);
            Ts[c4 + 0][r] = v.x; Ts[c4 + 1][r] = v.y;
            Ts[c4 + 2][r] = v.z; Ts[c4 + 3][r] = v.w;
        }
    }
    __syncthreads();
    const int nl = t >> 2;
#pragma unroll
    for (int s = 0; s < 2; ++s) {
        const int koff = (t & 3) * 8 + s * 32;
        short8_t u;
#pragma unroll
        for (int j = 0; j < 8; ++j) u[j] = f2bf(Ts[nl][koff + j]);
        *(short8_t*)(out + (size_t)(n0 + nl) * D_MODEL + k0 + koff) = u;
    }
}

// ---------------------------------------------------------------------------
// Kernel 1: QKV GEMM (m97 structure). Q pre-scaled by (1/8)*log2(e) so the
// attention softmax can run in exp2 domain. Q/K and V epilogues round-trip
// through wave-private LDS for coalesced dwordx4 stores.
// ---------------------------------------------------------------------------
__global__ __launch_bounds__(256, 3) void qkv_mfma_gemm_kernel(
    const short* __restrict__ xb,
    const short* __restrict__ wt,
    short* __restrict__ qkv)
{
    const int mBlock = blockIdx.x * 128;
    const int nBlock = blockIdx.y * 128;
    const int which  = blockIdx.z;
    const short* Bt = wt + (size_t)which * W_ELEMS;
    short* outBase  = qkv + (size_t)which * MAT_ELEMS;

    __shared__ short As[128 * 32];               // [m][k] contiguous, 8 KB
    __shared__ short Bs[128 * 32];               // [n][k] contiguous, 8 KB
    __shared__ __align__(16) short Es[4][64 * 72]; // per-wave epilogue, 36 KB

    const int t    = threadIdx.x;
    const int w    = t >> 6;
    const int lane = t & 63;
    const int n16  = lane & 15;
    const int quad = lane >> 4;
    const int mq   = (w & 1) * 64;
    const int nq   = (w >> 1) * 64;

    f32x4 acc[4][4];
#pragma unroll
    for (int i = 0; i < 4; ++i)
#pragma unroll
        for (int j = 0; j < 4; ++j) acc[i][j] = (f32x4){0.f, 0.f, 0.f, 0.f};

    const int off0 = w * 2048 + lane * 16;       // bytes
    const int off1 = off0 + 1024;
    const int r0s = off0 >> 6, k0s = (off0 & 63) >> 1;
    const int r1s = off1 >> 6, k1s = (off1 & 63) >> 1;
    const short* gA0 = xb + (size_t)(mBlock + r0s) * D_MODEL + k0s;
    const short* gA1 = xb + (size_t)(mBlock + r1s) * D_MODEL + k1s;
    const short* gB0 = Bt + (size_t)(nBlock + r0s) * D_MODEL + k0s;
    const short* gB1 = Bt + (size_t)(nBlock + r1s) * D_MODEL + k1s;
    short* lA0 = As + w * 1024;
    short* lA1 = As + w * 1024 + 512;
    short* lB0 = Bs + w * 1024;
    short* lB1 = Bs + w * 1024 + 512;

    for (int k0 = 0; k0 < D_MODEL; k0 += 32) {
        __syncthreads();
        GLD_LDS16(gA0 + k0, lA0);
        GLD_LDS16(gA1 + k0, lA1);
        GLD_LDS16(gB0 + k0, lB0);
        GLD_LDS16(gB1 + k0, lB1);
        __syncthreads();

        short8_t af[4], bf[4];
#pragma unroll
        for (int mt = 0; mt < 4; ++mt)
            af[mt] = *(const short8_t*)&As[(mq + mt * 16 + n16) * 32 + quad * 8];
#pragma unroll
        for (int nt = 0; nt < 4; ++nt)
            bf[nt] = *(const short8_t*)&Bs[(nq + nt * 16 + n16) * 32 + quad * 8];
#pragma unroll
        for (int mt = 0; mt < 4; ++mt)
#pragma unroll
            for (int nt = 0; nt < 4; ++nt)
                acc[mt][nt] = __builtin_amdgcn_mfma_f32_16x16x32_bf16(
                    af[mt], bf[nt], acc[mt][nt], 0, 0, 0);
    }

    // fold 1/sqrt(DH) AND log2(e) into Q (softmax runs in exp2 domain)
    const float oscale = (which == 0) ? 0.125f * 1.44269504089f : 1.0f;
    short* E = &Es[w][0];
    const int h  = (nBlock + nq) >> 6;           // head: fixed per wave tile
    const int m0 = mBlock + mq;                  // 64-aligned
    const int bb = m0 >> 11, ss0 = m0 & 2047;    // tile never crosses b
    const int rsub = lane >> 3;                  // 0..7
    const int ch   = lane & 7;                   // 0..7 (16B chunk)

    if (which < 2) {
        // ---- stage bf16 tile in wave-private LDS [s_local][dh], pad 72 ----
#pragma unroll
        for (int mt = 0; mt < 4; ++mt)
#pragma unroll
            for (int nt = 0; nt < 4; ++nt) {
                const int dhl = nt * 16 + n16;
#pragma unroll
                for (int reg = 0; reg < 4; ++reg) {
                    const int ml = mt * 16 + quad * 4 + reg;
                    E[ml * 72 + dhl] = f2bf(acc[mt][nt][reg] * oscale);
                }
            }
        // wave-private: no barrier needed; lgkmcnt orders write->read
        short* orow = outBase + ((size_t)(bb * N_HEADS + h) * S_LEN + ss0) * D_HEAD
                      + ch * 8;
#pragma unroll
        for (int it = 0; it < 8; ++it) {
            const int row = it * 8 + rsub;       // s_local
            const short8_t v = *(const short8_t*)&E[row * 72 + ch * 8];
            *(short8_t*)(orow + (size_t)row * D_HEAD) = v;
        }
    } else {
        // ---- V transposed (b,h,dh,s): stage [dh_local][s_local], pad 72 ----
#pragma unroll
        for (int mt = 0; mt < 4; ++mt)
#pragma unroll
            for (int nt = 0; nt < 4; ++nt) {
                const int dhl = nt * 16 + n16;
                const int sl0 = mt * 16 + quad * 4;
                short4_t u;
                u[0] = f2bf(acc[mt][nt][0]); u[1] = f2bf(acc[mt][nt][1]);
                u[2] = f2bf(acc[mt][nt][2]); u[3] = f2bf(acc[mt][nt][3]);
                *(short4_t*)&E[dhl * 72 + sl0] = u;
            }
        // coalesced: 8 lanes x 16B = 128B contiguous in s per dh-row
        short* orow = outBase + ((size_t)(bb * N_HEADS + h) * D_HEAD) * S_LEN
                      + ss0 + ch * 8;
#pragma unroll
        for (int it = 0; it < 8; ++it) {
            const int dhl = it * 8 + rsub;       // dh_local 0..63
            const short8_t v = *(const short8_t*)&E[dhl * 72 + ch * 8];
            *(short8_t*)(orow + (size_t)dhl * S_LEN) = v;
        }
    }
}

// ---------------------------------------------------------------------------
// Kernel 2: causal flash attention via bf16 MFMA, v10 (key-split).
// Diagnosis across v3-v8: per-CU throughput pinned ~0.6 tiles/kcy with DS
// pipe ~70%+ utilized (16x ds_read_b128 + P roundtrip + shfl per wave-tile,
// K/V frags read 4x redundantly since all waves covered all 64 keys).
// v10: wave w owns keys [16w,16w+16) of EVERY tile, and ALL 64 q rows of the
// block (Q + O accumulator live in registers). K frag reads: 8 b128 -> 2 b128;
// V: 8 b128 -> 4 b64. PV uses v_mfma_f32_16x16x16_bf16 (k=16 keys), whose
// B-fragment layout (k=quad*4+j, col=n) EXACTLY matches the swapped-QK C
// layout (key=quad*4+r, q=n): P never leaves the lane; Ps roundtrip deleted.
// Per-wave online softmax over its key subset; 4 partials merged per pass
// through LDS (flash-decoding combine). All-masked-subtile NaN guard: mask
// with -inf, floor m/mx at -1e30.
// Keeps: staged XOR-swizzled K/V, 2-barrier loop, exp2 softmax, defer-max,
// setprio, paired LPT grid (32 bh x 16 pairs), 256 threads.
// ---------------------------------------------------------------------------
__global__ __launch_bounds__(256, 2) void attn_mfma_kernel(
    const short* __restrict__ qkv,
    float* __restrict__ out)
{
    const int bh   = blockIdx.x;
    const int pr   = blockIdx.y;          // pair index 0..15
    const int t    = threadIdx.x;
    const int w    = t >> 6;
    const int lane = t & 63;
    const int n    = lane & 15;
    const int quad = lane >> 4;

    const short* Q  = qkv + (size_t)bh * HEAD_ELEMS;
    const short* K  = qkv + MAT_ELEMS + (size_t)bh * HEAD_ELEMS;
    const short* Vt = qkv + 2 * MAT_ELEMS + (size_t)bh * HEAD_ELEMS;  // (dh,s)

    __shared__ __align__(16) short Ks[64 * 64];   // swizzled [key][dh-chunk] 8KB
    __shared__ __align__(16) short Vs[64 * 64];   // swizzled [dh][key-chunk] 8KB
    __shared__ __align__(16) float Ob[64 * 68];   // merge buffer [q][dh] 17KB
    __shared__ float Mw[4][64];                   // per-wave m partial
    __shared__ float Lw[4][64];                   // per-wave l partial

    // --- staging: wave w stages rows [16w,16w+16) of K and V, 2 insts each ---
    const int srow0 = w * 16 + (lane >> 3);              // inst-0 row
    const int srow1 = srow0 + 8;                         // inst-1 row
    const int sd0 = ((lane & 7) ^ (srow0 & 7)) * 8;      // swizzled src offset
    const int sd1 = ((lane & 7) ^ (srow1 & 7)) * 8;
    const short* gK0 = K + srow0 * 64 + sd0;             // += j0*64 per tile
    const short* gK1 = K + srow1 * 64 + sd1;
    const short* gV0 = Vt + (size_t)srow0 * S_LEN + sd0; // += j0 per tile
    const short* gV1 = Vt + (size_t)srow1 * S_LEN + sd1;
    short* lK0 = Ks + (w * 16) * 64;
    short* lK1 = Ks + (w * 16 + 8) * 64;
    short* lV0 = Vs + (w * 16) * 64;
    short* lV1 = Vs + (w * 16 + 8) * 64;

    // K frag read: row 16w+n, logical chunk quad (dh 0..31) / quad+4 (32..63);
    // physical chunk = logical ^ (n&7)  ->  pcK shorts, pcK^32 shorts.
    const int pcK = ((quad ^ (n & 7))) * 8;
    // V frag read (16x16x16 A): row f*16+n, keys 16w+quad*4..+4:
    // logical chunk 2w+(quad>>1), phys ^ (n&7), +8B when quad odd.
    const int vphys = ((2 * w + (quad >> 1)) ^ (n & 7)) * 8 + (quad & 1) * 4;

    const int bb = bh >> 4;
    const int hh = bh & 15;
    const int kw = 16 * w + quad * 4;     // wave's key offset for this lane

    for (int pass = 0; pass < 2; ++pass) {
        const int qb = pass ? (31 - pr) : pr;

        // Q fragments for all 4 q-groups (Q pre-scaled by log2e/8 in GEMM)
        short8_t bq[4][2];
#pragma unroll
        for (int qg = 0; qg < 4; ++qg) {
            const short* qp = Q + (size_t)(qb * 64 + qg * 16 + n) * D_HEAD + quad * 8;
            bq[qg][0] = *(const short8_t*)(qp);
            bq[qg][1] = *(const short8_t*)(qp + 32);
        }

        float m[4], l[4];
        f32x4 o[4][4];                    // [dh-group f][q-group qg]
#pragma unroll
        for (int qg = 0; qg < 4; ++qg) { m[qg] = -1e30f; l[qg] = 0.f; }
#pragma unroll
        for (int f = 0; f < 4; ++f)
#pragma unroll
            for (int qg = 0; qg < 4; ++qg) o[f][qg] = (f32x4){0.f, 0.f, 0.f, 0.f};

        for (int tile = 0; tile <= qb; ++tile) {
            const int j0 = tile * 64;
            __syncthreads();                       // prior LDS reads done
            GLD_LDS16(gK0 + j0 * 64, lK0);
            GLD_LDS16(gK1 + j0 * 64, lK1);
            GLD_LDS16(gV0 + j0, lV0);
            GLD_LDS16(gV1 + j0, lV1);
            __syncthreads();                       // vmcnt drained by barrier

            // ---- S^T: wave's 16 keys x all 64 q (2 b128 K reads total) ----
            const int krow = (16 * w + n) * 64;
            const short8_t a0 = *(const short8_t*)&Ks[krow + pcK];
            const short8_t a1 = *(const short8_t*)&Ks[krow + (pcK ^ 32)];
            f32x4 st[4];
            __builtin_amdgcn_s_setprio(1);
#pragma unroll
            for (int qg = 0; qg < 4; ++qg) {
                f32x4 acc = (f32x4){0.f, 0.f, 0.f, 0.f};
                acc = __builtin_amdgcn_mfma_f32_16x16x32_bf16(a0, bq[qg][0], acc, 0, 0, 0);
                acc = __builtin_amdgcn_mfma_f32_16x16x32_bf16(a1, bq[qg][1], acc, 0, 0, 0);
                st[qg] = acc;
            }
            __builtin_amdgcn_s_setprio(0);

            // ---- mask (diagonal tile) + per-qg max over wave's 16 keys ----
            float mx[4];
            const bool diag = (tile == qb);
#pragma unroll
            for (int qg = 0; qg < 4; ++qg) {
                if (diag) {
#pragma unroll
                    for (int r = 0; r < 4; ++r)
                        st[qg][r] = (kw + r <= qg * 16 + n) ? st[qg][r]
                                                            : -__builtin_inff();
                }
                float mxq = fmaxf(fmaxf(st[qg][0], st[qg][1]),
                                  fmaxf(st[qg][2], st[qg][3]));
                mxq = fmaxf(mxq, __shfl_xor(mxq, 16));
                mxq = fmaxf(mxq, __shfl_xor(mxq, 32));
                mx[qg] = fmaxf(mxq, -1e30f);       // finite floor (NaN guard)
            }

            const bool ok = (mx[0] <= m[0] + 8.0f) && (mx[1] <= m[1] + 8.0f) &&
                            (mx[2] <= m[2] + 8.0f) && (mx[3] <= m[3] + 8.0f);
            float pv[4][4];
            if (__all(ok)) {
                // defer-max: keep old m, no rescale. P bounded by 2^8.
#pragma unroll
                for (int qg = 0; qg < 4; ++qg) {
                    float ls = 0.f;
#pragma unroll
                    for (int r = 0; r < 4; ++r) {
                        pv[qg][r] = __builtin_amdgcn_exp2f(st[qg][r] - m[qg]);
                        ls += pv[qg][r];
                    }
                    ls += __shfl_xor(ls, 16);
                    ls += __shfl_xor(ls, 32);
                    l[qg] += ls;
                }
            } else {
#pragma unroll
                for (int qg = 0; qg < 4; ++qg) {
                    const float mnew  = fmaxf(m[qg], mx[qg]);
                    const float alpha = __builtin_amdgcn_exp2f(m[qg] - mnew);
                    float ls = 0.f;
#pragma unroll
                    for (int r = 0; r < 4; ++r) {
                        pv[qg][r] = __builtin_amdgcn_exp2f(st[qg][r] - mnew);
                        ls += pv[qg][r];
                    }
                    ls += __shfl_xor(ls, 16);
                    ls += __shfl_xor(ls, 32);
                    l[qg] = l[qg] * alpha + ls;
                    m[qg] = mnew;
#pragma unroll
                    for (int f = 0; f < 4; ++f) {
                        o[f][qg][0] *= alpha; o[f][qg][1] *= alpha;
                        o[f][qg][2] *= alpha; o[f][qg][3] *= alpha;
                    }
                }
            }

            // ---- pack P in-lane (k=quad*4+r matches 16x16x16 B-frag) ----
            short4_t pf[4];
#pragma unroll
            for (int qg = 0; qg < 4; ++qg) {
                const unsigned int b0 = __builtin_bit_cast(unsigned int, pv[qg][0]);
                const unsigned int b1 = __builtin_bit_cast(unsigned int, pv[qg][1]);
                const unsigned int b2 = __builtin_bit_cast(unsigned int, pv[qg][2]);
                const unsigned int b3 = __builtin_bit_cast(unsigned int, pv[qg][3]);
                uint2 pk;
                pk.x = (b0 >> 16) | (b1 & 0xffff0000u);
                pk.y = (b2 >> 16) | (b3 & 0xffff0000u);
                pf[qg] = __builtin_bit_cast(short4_t, pk);
            }

            // ---- O^T[dh][q] += V^T[dh][wave keys] . P (4 b64 V reads) ----
            __builtin_amdgcn_s_setprio(1);
#pragma unroll
            for (int f = 0; f < 4; ++f) {
                const short4_t va = *(const short4_t*)&Vs[(f * 16 + n) * 64 + vphys];
#pragma unroll
                for (int qg = 0; qg < 4; ++qg)
                    o[f][qg] = mfma16_bf16(va, pf[qg], o[f][qg]);
            }
            __builtin_amdgcn_s_setprio(0);
        }

        // ---- merge 4 wave partials (flash-decoding combine) ----
        __syncthreads();                           // all K/V LDS reads done
        if (quad == 0) {
#pragma unroll
            for (int qg = 0; qg < 4; ++qg) {
                Mw[w][qg * 16 + n] = m[qg];
                Lw[w][qg * 16 + n] = l[qg];
            }
        }
        __syncthreads();
        float aw[4];
#pragma unroll
        for (int qg = 0; qg < 4; ++qg) {
            const int q = qg * 16 + n;
            const float M = fmaxf(fmaxf(Mw[0][q], Mw[1][q]),
                                  fmaxf(Mw[2][q], Mw[3][q]));
            aw[qg] = __builtin_amdgcn_exp2f(m[qg] - M);
        }
#pragma unroll
        for (int f = 0; f < 4; ++f)
#pragma unroll
            for (int qg = 0; qg < 4; ++qg) {
                o[f][qg][0] *= aw[qg]; o[f][qg][1] *= aw[qg];
                o[f][qg][2] *= aw[qg]; o[f][qg][3] *= aw[qg];
            }
        // 4 rounds: wave w handles q-quadrant w^rr (init at rr=0, add after)
#pragma unroll
        for (int rr = 0; rr < 4; ++rr) {
            const int qg = w ^ rr;
            if (rr == 0) {
#pragma unroll
                for (int f = 0; f < 4; ++f)
                    *(f32x4*)&Ob[(qg * 16 + n) * 68 + f * 16 + quad * 4] = o[f][qg];
            } else {
#pragma unroll
                for (int f = 0; f < 4; ++f) {
                    float* pOb = &Ob[(qg * 16 + n) * 68 + f * 16 + quad * 4];
                    f32x4 x = *(f32x4*)pOb;
                    x[0] += o[f][qg][0]; x[1] += o[f][qg][1];
                    x[2] += o[f][qg][2]; x[3] += o[f][qg][3];
                    *(f32x4*)pOb = x;
                }
            }
            __syncthreads();
        }

        // ---- normalize + store: thread t -> (row = t>>2, 16-float chunk) ----
        {
            const int row = t >> 2;                // q row 0..63
            const int c   = t & 3;
            const float M = fmaxf(fmaxf(Mw[0][row], Mw[1][row]),
                                  fmaxf(Mw[2][row], Mw[3][row]));
            float lt = 0.f;
#pragma unroll
            for (int wv = 0; wv < 4; ++wv)
                lt += __builtin_amdgcn_exp2f(Mw[wv][row] - M) * Lw[wv][row];
            const float inv = 1.0f / lt;
            float* op = out + ((size_t)(bb * S_LEN + qb * 64 + row)) * D_MODEL
                        + hh * D_HEAD + c * 16;
#pragma unroll
            for (int j = 0; j < 4; ++j) {
                f32x4 x = *(f32x4*)&Ob[row * 68 + c * 16 + j * 4];
                x[0] *= inv; x[1] *= inv; x[2] *= inv; x[3] *= inv;
                *(f32x4*)(op + j * 4) = x;
            }
        }
        // next pass's tile loop begins with __syncthreads -> safe to restage
    }
}

// ---------------------------------------------------------------------------
extern "C" void kernel_launch(void* const* d_in, const int* in_sizes, int n_in,
                              void* d_out, int out_size, void* d_ws, size_t ws_size,
                              hipStream_t stream) {
    const float* x  = (const float*)d_in[0];
    const float* Wq = (const float*)d_in[1];
    const float* Wk = (const float*)d_in[2];
    const float* Wv = (const float*)d_in[3];
    float* out = (float*)d_out;

    // workspace: xb (8MB) | wt (6MB) | qkv (24MB) = 38MB
    short* xb  = (short*)d_ws;
    short* wt  = xb + MAT_ELEMS;
    short* qkv = wt + 3 * W_ELEMS;

    convert_x_kernel<<<dim3(MAT_ELEMS / (256 * 8)), 256, 0, stream>>>(x, xb);
    transpose_w_kernel<<<dim3(16, 16, 3), 256, 0, stream>>>(Wq, Wk, Wv, wt);

    qkv_mfma_gemm_kernel<<<dim3(32, 8, 3), 256, 0, stream>>>(xb, wt, qkv);

    attn_mfma_kernel<<<dim3(2 * N_HEADS, 16), 256, 0, stream>>>(qkv, out);
}

// Round 8
// 168.650 us; speedup vs baseline: 1.8452x; 1.8452x over previous
//
#include <hip/hip_runtime.h>
#include <hip/hip_bf16.h>

// B=2, S=2048, D=1024, H=16, DH=64. fp32 in/out; bf16 MFMA internals.
#define S_LEN   2048
#define D_MODEL 1024
#define N_HEADS 16
#define D_HEAD  64
#define HEAD_ELEMS (2048ull * 64ull)          // elements per (b,h) plane
#define MAT_ELEMS  (4096ull * 1024ull)        // one projected matrix (Q/K/V)
#define W_ELEMS    (1024ull * 1024ull)        // one weight matrix

typedef __attribute__((ext_vector_type(8))) short short8_t;   // 8 bf16
typedef __attribute__((ext_vector_type(4))) short short4_t;   // 4 bf16
typedef __attribute__((ext_vector_type(4))) float f32x4;      // MFMA C/D frag

__device__ __forceinline__ short f2bf(float f) {
    __hip_bfloat16 h = __float2bfloat16(f);
    union { __hip_bfloat16 h; short s; } cv;
    cv.h = h;
    return cv.s;
}

// v_mfma_f32_16x16x16_bf16 via inline asm (validated on HW in v10: passed).
__device__ __forceinline__ f32x4 mfma16_bf16(short4_t a, short4_t b, f32x4 c) {
    f32x4 d;
    asm("v_mfma_f32_16x16x16_bf16 %0, %1, %2, %3"
        : "=v"(d) : "v"(a), "v"(b), "0"(c));
    return d;
}

// global_load_lds width=16: LDS dest = wave-uniform base + lane*16
#define GLD_LDS16(gptr, lptr) \
    __builtin_amdgcn_global_load_lds( \
        (const __attribute__((address_space(1))) unsigned int*)(gptr), \
        (__attribute__((address_space(3))) unsigned int*)(lptr), 16, 0, 0)

// ---------------------------------------------------------------------------
// Kernel 0a: convert x fp32 -> bf16.
// ---------------------------------------------------------------------------
__global__ __launch_bounds__(256) void convert_x_kernel(
    const float* __restrict__ x, short* __restrict__ xb)
{
    const int i = (blockIdx.x * 256 + threadIdx.x) * 8;
    const float4 v0 = *(const float4*)(x + i);
    const float4 v1 = *(const float4*)(x + i + 4);
    short8_t u;
    u[0] = f2bf(v0.x); u[1] = f2bf(v0.y); u[2] = f2bf(v0.z); u[3] = f2bf(v0.w);
    u[4] = f2bf(v1.x); u[5] = f2bf(v1.y); u[6] = f2bf(v1.z); u[7] = f2bf(v1.w);
    *(short8_t*)(xb + i) = u;
}

// ---------------------------------------------------------------------------
// Kernel 0b: convert + transpose W fp32[k][n] -> bf16 Wt[n][k].
// ---------------------------------------------------------------------------
__global__ __launch_bounds__(256) void transpose_w_kernel(
    const float* __restrict__ Wq, const float* __restrict__ Wk,
    const float* __restrict__ Wv, short* __restrict__ wt)
{
    const int k0 = blockIdx.x * 64;
    const int n0 = blockIdx.y * 64;
    const int which = blockIdx.z;
    const float* W = (which == 0) ? Wq : (which == 1) ? Wk : Wv;
    short* out = wt + (size_t)which * W_ELEMS;

    __shared__ float Ts[64][68];   // [n_local][k_local]
    const int t = threadIdx.x;
    {
        const int c4 = (t & 15) * 4;
#pragma unroll
        for (int i = 0; i < 4; ++i) {
            const int r = (t >> 4) + i * 16;
            const float4 v = *(const float4*)(W + (size_t)(k0 + r) * D_MODEL + n0 + c4);
            Ts[c4 + 0][r] = v.x; Ts[c4 + 1][r] = v.y;
            Ts[c4 + 2][r] = v.z; Ts[c4 + 3][r] = v.w;
        }
    }
    __syncthreads();
    const int nl = t >> 2;
#pragma unroll
    for (int s = 0; s < 2; ++s) {
        const int koff = (t & 3) * 8 + s * 32;
        short8_t u;
#pragma unroll
        for (int j = 0; j < 8; ++j) u[j] = f2bf(Ts[nl][koff + j]);
        *(short8_t*)(out + (size_t)(n0 + nl) * D_MODEL + k0 + koff) = u;
    }
}

// ---------------------------------------------------------------------------
// Kernel 1: QKV GEMM (m97 structure). Q pre-scaled by (1/8)*log2(e) so the
// attention softmax can run in exp2 domain. Q/K and V epilogues round-trip
// through wave-private LDS for coalesced dwordx4 stores.
// ---------------------------------------------------------------------------
__global__ __launch_bounds__(256, 3) void qkv_mfma_gemm_kernel(
    const short* __restrict__ xb,
    const short* __restrict__ wt,
    short* __restrict__ qkv)
{
    const int mBlock = blockIdx.x * 128;
    const int nBlock = blockIdx.y * 128;
    const int which  = blockIdx.z;
    const short* Bt = wt + (size_t)which * W_ELEMS;
    short* outBase  = qkv + (size_t)which * MAT_ELEMS;

    __shared__ short As[128 * 32];               // [m][k] contiguous, 8 KB
    __shared__ short Bs[128 * 32];               // [n][k] contiguous, 8 KB
    __shared__ __align__(16) short Es[4][64 * 72]; // per-wave epilogue, 36 KB

    const int t    = threadIdx.x;
    const int w    = t >> 6;
    const int lane = t & 63;
    const int n16  = lane & 15;
    const int quad = lane >> 4;
    const int mq   = (w & 1) * 64;
    const int nq   = (w >> 1) * 64;

    f32x4 acc[4][4];
#pragma unroll
    for (int i = 0; i < 4; ++i)
#pragma unroll
        for (int j = 0; j < 4; ++j) acc[i][j] = (f32x4){0.f, 0.f, 0.f, 0.f};

    const int off0 = w * 2048 + lane * 16;       // bytes
    const int off1 = off0 + 1024;
    const int r0s = off0 >> 6, k0s = (off0 & 63) >> 1;
    const int r1s = off1 >> 6, k1s = (off1 & 63) >> 1;
    const short* gA0 = xb + (size_t)(mBlock + r0s) * D_MODEL + k0s;
    const short* gA1 = xb + (size_t)(mBlock + r1s) * D_MODEL + k1s;
    const short* gB0 = Bt + (size_t)(nBlock + r0s) * D_MODEL + k0s;
    const short* gB1 = Bt + (size_t)(nBlock + r1s) * D_MODEL + k1s;
    short* lA0 = As + w * 1024;
    short* lA1 = As + w * 1024 + 512;
    short* lB0 = Bs + w * 1024;
    short* lB1 = Bs + w * 1024 + 512;

    for (int k0 = 0; k0 < D_MODEL; k0 += 32) {
        __syncthreads();
        GLD_LDS16(gA0 + k0, lA0);
        GLD_LDS16(gA1 + k0, lA1);
        GLD_LDS16(gB0 + k0, lB0);
        GLD_LDS16(gB1 + k0, lB1);
        __syncthreads();

        short8_t af[4], bf[4];
#pragma unroll
        for (int mt = 0; mt < 4; ++mt)
            af[mt] = *(const short8_t*)&As[(mq + mt * 16 + n16) * 32 + quad * 8];
#pragma unroll
        for (int nt = 0; nt < 4; ++nt)
            bf[nt] = *(const short8_t*)&Bs[(nq + nt * 16 + n16) * 32 + quad * 8];
#pragma unroll
        for (int mt = 0; mt < 4; ++mt)
#pragma unroll
            for (int nt = 0; nt < 4; ++nt)
                acc[mt][nt] = __builtin_amdgcn_mfma_f32_16x16x32_bf16(
                    af[mt], bf[nt], acc[mt][nt], 0, 0, 0);
    }

    // fold 1/sqrt(DH) AND log2(e) into Q (softmax runs in exp2 domain)
    const float oscale = (which == 0) ? 0.125f * 1.44269504089f : 1.0f;
    short* E = &Es[w][0];
    const int h  = (nBlock + nq) >> 6;           // head: fixed per wave tile
    const int m0 = mBlock + mq;                  // 64-aligned
    const int bb = m0 >> 11, ss0 = m0 & 2047;    // tile never crosses b
    const int rsub = lane >> 3;                  // 0..7
    const int ch   = lane & 7;                   // 0..7 (16B chunk)

    if (which < 2) {
        // ---- stage bf16 tile in wave-private LDS [s_local][dh], pad 72 ----
#pragma unroll
        for (int mt = 0; mt < 4; ++mt)
#pragma unroll
            for (int nt = 0; nt < 4; ++nt) {
                const int dhl = nt * 16 + n16;
#pragma unroll
                for (int reg = 0; reg < 4; ++reg) {
                    const int ml = mt * 16 + quad * 4 + reg;
                    E[ml * 72 + dhl] = f2bf(acc[mt][nt][reg] * oscale);
                }
            }
        // wave-private: no barrier needed; lgkmcnt orders write->read
        short* orow = outBase + ((size_t)(bb * N_HEADS + h) * S_LEN + ss0) * D_HEAD
                      + ch * 8;
#pragma unroll
        for (int it = 0; it < 8; ++it) {
            const int row = it * 8 + rsub;       // s_local
            const short8_t v = *(const short8_t*)&E[row * 72 + ch * 8];
            *(short8_t*)(orow + (size_t)row * D_HEAD) = v;
        }
    } else {
        // ---- V transposed (b,h,dh,s): stage [dh_local][s_local], pad 72 ----
#pragma unroll
        for (int mt = 0; mt < 4; ++mt)
#pragma unroll
            for (int nt = 0; nt < 4; ++nt) {
                const int dhl = nt * 16 + n16;
                const int sl0 = mt * 16 + quad * 4;
                short4_t u;
                u[0] = f2bf(acc[mt][nt][0]); u[1] = f2bf(acc[mt][nt][1]);
                u[2] = f2bf(acc[mt][nt][2]); u[3] = f2bf(acc[mt][nt][3]);
                *(short4_t*)&E[dhl * 72 + sl0] = u;
            }
        // coalesced: 8 lanes x 16B = 128B contiguous in s per dh-row
        short* orow = outBase + ((size_t)(bb * N_HEADS + h) * D_HEAD) * S_LEN
                      + ss0 + ch * 8;
#pragma unroll
        for (int it = 0; it < 8; ++it) {
            const int dhl = it * 8 + rsub;       // dh_local 0..63
            const short8_t v = *(const short8_t*)&E[dhl * 72 + ch * 8];
            *(short8_t*)(orow + (size_t)dhl * S_LEN) = v;
        }
    }
}

// ---------------------------------------------------------------------------
// Kernel 2: causal flash attention via bf16 MFMA, v11 (key+q split).
// v10 post-mortem: key-split with ALL 64 q per wave = o[4][4]+bq[4][2] = 96+
// VGPR -> spilled to scratch (WRITE_SIZE 1.2GB, 83% HBM). But v10 PASSED, so
// its mechanisms are HW-validated: mfma16 asm, in-lane P (QK C-layout ==
// mfma16 B-frag), swizzled V b64 reads, key-split merge.
// v11 = same economy, half the registers: 8 waves (512 thr), wave (kq=w&3,
// qh=w>>2) owns 16 keys x 32 q rows. o[4][2]=32 VGPR, bq[2][2]=16 -> fits
// under the 128-VGPR cap (launch_bounds(512,4), 2 blocks/CU).
// ONE shared K/V tile per round serves all 8 waves (2 staging insts/wave),
// K/V read redundancy 4x -> 2x, P LDS round-trip deleted.
// Merge: 4 key-partials per q-half, flash-decoding combine through Ob.
// Keeps: staged XOR-swizzled K/V, 2-barrier loop, exp2 softmax, defer-max,
// setprio, paired LPT grid (32 bh x 16 pairs).
// ---------------------------------------------------------------------------
__global__ __launch_bounds__(512, 4) void attn_mfma_kernel(
    const short* __restrict__ qkv,
    float* __restrict__ out)
{
    const int bh   = blockIdx.x;
    const int pr   = blockIdx.y;          // pair index 0..15
    const int t    = threadIdx.x;         // 0..511
    const int w    = t >> 6;              // 0..7
    const int kq   = w & 3;               // key-quarter
    const int qh   = w >> 2;              // q-half
    const int lane = t & 63;
    const int n    = lane & 15;
    const int quad = lane >> 4;

    const short* Q  = qkv + (size_t)bh * HEAD_ELEMS;
    const short* K  = qkv + MAT_ELEMS + (size_t)bh * HEAD_ELEMS;
    const short* Vt = qkv + 2 * MAT_ELEMS + (size_t)bh * HEAD_ELEMS;  // (dh,s)

    __shared__ __align__(16) short Ks[64 * 64];   // swizzled [key][dh-chunk] 8KB
    __shared__ __align__(16) short Vs[64 * 64];   // swizzled [dh][key-chunk] 8KB
    __shared__ __align__(16) float Ob[64 * 68];   // merge buffer [q][dh] 17KB
    __shared__ float Mw[4][64];                   // per-kq m partial
    __shared__ float Lw[4][64];                   // per-kq l partial

    // --- staging: wave w stages rows [8w, 8w+8) of K and of V, 1 inst each ---
    const int srow = 8 * w + (lane >> 3);                // 0..63
    const int sd   = ((lane & 7) ^ (srow & 7)) * 8;      // swizzled src offset
    const short* gK = K + srow * 64 + sd;                // += j0*64 per tile
    const short* gV = Vt + (size_t)srow * S_LEN + sd;    // += j0 per tile
    short* lK = Ks + (8 * w) * 64;
    short* lV = Vs + (8 * w) * 64;

    // K frag read: row 16kq+n, phys chunk = logical ^ (n&7)
    const int pcK = ((quad ^ (n & 7))) * 8;
    // V frag read (mfma16 A): row f*16+n, keys 16kq+quad*4..+4:
    // logical chunk 2kq+(quad>>1), phys ^ (n&7), +4 shorts when quad odd.
    const int vphys = ((2 * kq + (quad >> 1)) ^ (n & 7)) * 8 + (quad & 1) * 4;

    const int bb = bh >> 4;
    const int hh = bh & 15;
    const int kwl = 16 * kq + quad * 4;   // wave's key offset for this lane

    for (int pass = 0; pass < 2; ++pass) {
        const int qb = pass ? (31 - pr) : pr;

        // Q fragments for the wave's 2 q-groups (pre-scaled by log2e/8)
        short8_t bq[2][2];
#pragma unroll
        for (int qg = 0; qg < 2; ++qg) {
            const short* qp = Q + (size_t)(qb * 64 + qh * 32 + qg * 16 + n) * D_HEAD
                              + quad * 8;
            bq[qg][0] = *(const short8_t*)(qp);
            bq[qg][1] = *(const short8_t*)(qp + 32);
        }

        float m[2], l[2];
        f32x4 o[4][2];                    // [dh-group f][q-group qg]
#pragma unroll
        for (int qg = 0; qg < 2; ++qg) { m[qg] = -1e30f; l[qg] = 0.f; }
#pragma unroll
        for (int f = 0; f < 4; ++f)
#pragma unroll
            for (int qg = 0; qg < 2; ++qg) o[f][qg] = (f32x4){0.f, 0.f, 0.f, 0.f};

        for (int tile = 0; tile <= qb; ++tile) {
            const int j0 = tile * 64;
            __syncthreads();                       // prior LDS reads done
            GLD_LDS16(gK + j0 * 64, lK);
            GLD_LDS16(gV + j0, lV);
            __syncthreads();                       // vmcnt drained by barrier

            // ---- S^T: wave's 16 keys x its 32 q (2 b128 K reads) ----
            const int krow = (16 * kq + n) * 64;
            const short8_t a0 = *(const short8_t*)&Ks[krow + pcK];
            const short8_t a1 = *(const short8_t*)&Ks[krow + (pcK ^ 32)];
            f32x4 st[2];
            __builtin_amdgcn_s_setprio(1);
#pragma unroll
            for (int qg = 0; qg < 2; ++qg) {
                f32x4 acc = (f32x4){0.f, 0.f, 0.f, 0.f};
                acc = __builtin_amdgcn_mfma_f32_16x16x32_bf16(a0, bq[qg][0], acc, 0, 0, 0);
                acc = __builtin_amdgcn_mfma_f32_16x16x32_bf16(a1, bq[qg][1], acc, 0, 0, 0);
                st[qg] = acc;
            }
            __builtin_amdgcn_s_setprio(0);

            // ---- mask (diagonal tile) + per-qg max over wave's 16 keys ----
            float mx[2];
            const bool diag = (tile == qb);
#pragma unroll
            for (int qg = 0; qg < 2; ++qg) {
                if (diag) {
#pragma unroll
                    for (int r = 0; r < 4; ++r)
                        st[qg][r] = (kwl + r <= qh * 32 + qg * 16 + n)
                                        ? st[qg][r] : -__builtin_inff();
                }
                float mxq = fmaxf(fmaxf(st[qg][0], st[qg][1]),
                                  fmaxf(st[qg][2], st[qg][3]));
                mxq = fmaxf(mxq, __shfl_xor(mxq, 16));
                mxq = fmaxf(mxq, __shfl_xor(mxq, 32));
                mx[qg] = fmaxf(mxq, -1e30f);       // finite floor (NaN guard)
            }

            const bool ok = (mx[0] <= m[0] + 8.0f) && (mx[1] <= m[1] + 8.0f);
            float pv[2][4];
            if (__all(ok)) {
                // defer-max: keep old m, no rescale. P bounded by 2^8.
#pragma unroll
                for (int qg = 0; qg < 2; ++qg) {
                    float ls = 0.f;
#pragma unroll
                    for (int r = 0; r < 4; ++r) {
                        pv[qg][r] = __builtin_amdgcn_exp2f(st[qg][r] - m[qg]);
                        ls += pv[qg][r];
                    }
                    ls += __shfl_xor(ls, 16);
                    ls += __shfl_xor(ls, 32);
                    l[qg] += ls;
                }
            } else {
#pragma unroll
                for (int qg = 0; qg < 2; ++qg) {
                    const float mnew  = fmaxf(m[qg], mx[qg]);
                    const float alpha = __builtin_amdgcn_exp2f(m[qg] - mnew);
                    float ls = 0.f;
#pragma unroll
                    for (int r = 0; r < 4; ++r) {
                        pv[qg][r] = __builtin_amdgcn_exp2f(st[qg][r] - mnew);
                        ls += pv[qg][r];
                    }
                    ls += __shfl_xor(ls, 16);
                    ls += __shfl_xor(ls, 32);
                    l[qg] = l[qg] * alpha + ls;
                    m[qg] = mnew;
#pragma unroll
                    for (int f = 0; f < 4; ++f) {
                        o[f][qg][0] *= alpha; o[f][qg][1] *= alpha;
                        o[f][qg][2] *= alpha; o[f][qg][3] *= alpha;
                    }
                }
            }

            // ---- pack P in-lane (k=quad*4+r matches mfma16 B-frag) ----
            short4_t pf[2];
#pragma unroll
            for (int qg = 0; qg < 2; ++qg) {
                const unsigned int b0 = __builtin_bit_cast(unsigned int, pv[qg][0]);
                const unsigned int b1 = __builtin_bit_cast(unsigned int, pv[qg][1]);
                const unsigned int b2 = __builtin_bit_cast(unsigned int, pv[qg][2]);
                const unsigned int b3 = __builtin_bit_cast(unsigned int, pv[qg][3]);
                uint2 pk;
                pk.x = (b0 >> 16) | (b1 & 0xffff0000u);
                pk.y = (b2 >> 16) | (b3 & 0xffff0000u);
                pf[qg] = __builtin_bit_cast(short4_t, pk);
            }

            // ---- O^T[dh][q] += V^T[dh][wave keys] . P (4 b64 V reads) ----
            __builtin_amdgcn_s_setprio(1);
#pragma unroll
            for (int f = 0; f < 4; ++f) {
                const short4_t va = *(const short4_t*)&Vs[(f * 16 + n) * 64 + vphys];
#pragma unroll
                for (int qg = 0; qg < 2; ++qg)
                    o[f][qg] = mfma16_bf16(va, pf[qg], o[f][qg]);
            }
            __builtin_amdgcn_s_setprio(0);
        }

        // ---- merge 4 key-partials per q-half (flash-decoding combine) ----
        __syncthreads();                           // all K/V LDS reads done
        if (quad == 0) {
#pragma unroll
            for (int qg = 0; qg < 2; ++qg) {
                Mw[kq][qh * 32 + qg * 16 + n] = m[qg];
                Lw[kq][qh * 32 + qg * 16 + n] = l[qg];
            }
        }
        __syncthreads();
        float aw[2];
#pragma unroll
        for (int qg = 0; qg < 2; ++qg) {
            const int q = qh * 32 + qg * 16 + n;
            const float M = fmaxf(fmaxf(Mw[0][q], Mw[1][q]),
                                  fmaxf(Mw[2][q], Mw[3][q]));
            aw[qg] = __builtin_amdgcn_exp2f(m[qg] - M);
        }
#pragma unroll
        for (int f = 0; f < 4; ++f)
#pragma unroll
            for (int qg = 0; qg < 2; ++qg) {
                o[f][qg][0] *= aw[qg]; o[f][qg][1] *= aw[qg];
                o[f][qg][2] *= aw[qg]; o[f][qg][3] *= aw[qg];
            }
        // 4 rounds over kq: init at rr=0, add after (both q-halves disjoint)
#pragma unroll
        for (int rr = 0; rr < 4; ++rr) {
            if (kq == rr) {
#pragma unroll
                for (int qg = 0; qg < 2; ++qg) {
                    const int row = qh * 32 + qg * 16 + n;
#pragma unroll
                    for (int f = 0; f < 4; ++f) {
                        float* pOb = &Ob[row * 68 + f * 16 + quad * 4];
                        if (rr == 0) {
                            *(f32x4*)pOb = o[f][qg];
                        } else {
                            f32x4 x = *(f32x4*)pOb;
                            x[0] += o[f][qg][0]; x[1] += o[f][qg][1];
                            x[2] += o[f][qg][2]; x[3] += o[f][qg][3];
                            *(f32x4*)pOb = x;
                        }
                    }
                }
            }
            __syncthreads();
        }

        // ---- normalize + store: thread t -> (row = t>>3, 8-float chunk) ----
        {
            const int row = t >> 3;                // q row 0..63
            const int c8  = t & 7;                 // 0..7
            const float M = fmaxf(fmaxf(Mw[0][row], Mw[1][row]),
                                  fmaxf(Mw[2][row], Mw[3][row]));
            float lt = 0.f;
#pragma unroll
            for (int wv = 0; wv < 4; ++wv)
                lt += __builtin_amdgcn_exp2f(Mw[wv][row] - M) * Lw[wv][row];
            const float inv = 1.0f / lt;
            float* op = out + ((size_t)(bb * S_LEN + qb * 64 + row)) * D_MODEL
                        + hh * D_HEAD + c8 * 8;
#pragma unroll
            for (int j = 0; j < 2; ++j) {
                f32x4 x = *(f32x4*)&Ob[row * 68 + c8 * 8 + j * 4];
                x[0] *= inv; x[1] *= inv; x[2] *= inv; x[3] *= inv;
                *(f32x4*)(op + j * 4) = x;
            }
        }
        // next pass's tile loop begins with __syncthreads -> safe to restage
    }
}

// ---------------------------------------------------------------------------
extern "C" void kernel_launch(void* const* d_in, const int* in_sizes, int n_in,
                              void* d_out, int out_size, void* d_ws, size_t ws_size,
                              hipStream_t stream) {
    const float* x  = (const float*)d_in[0];
    const float* Wq = (const float*)d_in[1];
    const float* Wk = (const float*)d_in[2];
    const float* Wv = (const float*)d_in[3];
    float* out = (float*)d_out;

    // workspace: xb (8MB) | wt (6MB) | qkv (24MB) = 38MB
    short* xb  = (short*)d_ws;
    short* wt  = xb + MAT_ELEMS;
    short* qkv = wt + 3 * W_ELEMS;

    convert_x_kernel<<<dim3(MAT_ELEMS / (256 * 8)), 256, 0, stream>>>(x, xb);
    transpose_w_kernel<<<dim3(16, 16, 3), 256, 0, stream>>>(Wq, Wk, Wv, wt);

    qkv_mfma_gemm_kernel<<<dim3(32, 8, 3), 256, 0, stream>>>(xb, wt, qkv);

    attn_mfma_kernel<<<dim3(2 * N_HEADS, 16), 512, 0, stream>>>(qkv, out);
}

// Round 10
// 150.647 us; speedup vs baseline: 2.0657x; 1.1195x over previous
//
#include <hip/hip_runtime.h>
#include <hip/hip_bf16.h>

// B=2, S=2048, D=1024, H=16, DH=64. fp32 in/out; bf16 MFMA internals.
#define S_LEN   2048
#define D_MODEL 1024
#define N_HEADS 16
#define D_HEAD  64
#define HEAD_ELEMS (2048ull * 64ull)          // elements per (b,h) plane
#define MAT_ELEMS  (4096ull * 1024ull)        // one projected matrix (Q/K/V)
#define W_ELEMS    (1024ull * 1024ull)        // one weight matrix

typedef __attribute__((ext_vector_type(8))) short short8_t;   // 8 bf16
typedef __attribute__((ext_vector_type(4))) short short4_t;   // 4 bf16
typedef __attribute__((ext_vector_type(4))) float f32x4;      // MFMA C/D frag

__device__ __forceinline__ short f2bf(float f) {
    __hip_bfloat16 h = __float2bfloat16(f);
    union { __hip_bfloat16 h; short s; } cv;
    cv.h = h;
    return cv.s;
}

// v_mfma_f32_16x16x16_bf16. v13 post-mortem: raw inline asm under heavy unroll
// miscompiled (v10/v11 with identical math PASSED; v13 failed) — suspected
// missing hazard nops / operand-overlap in the asm black box. Use the
// INTRINSIC (compiler owns hazards + regalloc); hardened asm as fallback.
__device__ __forceinline__ f32x4 mfma16_bf16(short4_t a, short4_t b, f32x4 c) {
#if __has_builtin(__builtin_amdgcn_mfma_f32_16x16x16bf16_1k)
    return __builtin_amdgcn_mfma_f32_16x16x16bf16_1k(a, b, c, 0, 0, 0);
#elif __has_builtin(__builtin_amdgcn_mfma_f32_16x16x16_bf16)
    return __builtin_amdgcn_mfma_f32_16x16x16_bf16(a, b, c, 0, 0, 0);
#else
    f32x4 d;
    asm("s_nop 1\n\t"
        "v_mfma_f32_16x16x16_bf16 %0, %1, %2, %3"
        : "=&v"(d) : "v"(a), "v"(b), "0"(c));
    return d;
#endif
}

// global_load_lds width=16: LDS dest = wave-uniform base + lane*16
#define GLD_LDS16(gptr, lptr) \
    __builtin_amdgcn_global_load_lds( \
        (const __attribute__((address_space(1))) unsigned int*)(gptr), \
        (__attribute__((address_space(3))) unsigned int*)(lptr), 16, 0, 0)

// ---------------------------------------------------------------------------
// Kernel 0a: convert x fp32 -> bf16.
// ---------------------------------------------------------------------------
__global__ __launch_bounds__(256) void convert_x_kernel(
    const float* __restrict__ x, short* __restrict__ xb)
{
    const int i = (blockIdx.x * 256 + threadIdx.x) * 8;
    const float4 v0 = *(const float4*)(x + i);
    const float4 v1 = *(const float4*)(x + i + 4);
    short8_t u;
    u[0] = f2bf(v0.x); u[1] = f2bf(v0.y); u[2] = f2bf(v0.z); u[3] = f2bf(v0.w);
    u[4] = f2bf(v1.x); u[5] = f2bf(v1.y); u[6] = f2bf(v1.z); u[7] = f2bf(v1.w);
    *(short8_t*)(xb + i) = u;
}

// ---------------------------------------------------------------------------
// Kernel 0b: convert + transpose W fp32[k][n] -> bf16 Wt[n][k].
// ---------------------------------------------------------------------------
__global__ __launch_bounds__(256) void transpose_w_kernel(
    const float* __restrict__ Wq, const float* __restrict__ Wk,
    const float* __restrict__ Wv, short* __restrict__ wt)
{
    const int k0 = blockIdx.x * 64;
    const int n0 = blockIdx.y * 64;
    const int which = blockIdx.z;
    const float* W = (which == 0) ? Wq : (which == 1) ? Wk : Wv;
    short* out = wt + (size_t)which * W_ELEMS;

    __shared__ float Ts[64][68];   // [n_local][k_local]
    const int t = threadIdx.x;
    {
        const int c4 = (t & 15) * 4;
#pragma unroll
        for (int i = 0; i < 4; ++i) {
            const int r = (t >> 4) + i * 16;
            const float4 v = *(const float4*)(W + (size_t)(k0 + r) * D_MODEL + n0 + c4);
            Ts[c4 + 0][r] = v.x; Ts[c4 + 1][r] = v.y;
            Ts[c4 + 2][r] = v.z; Ts[c4 + 3][r] = v.w;
        }
    }
    __syncthreads();
    const int nl = t >> 2;
#pragma unroll
    for (int s = 0; s < 2; ++s) {
        const int koff = (t & 3) * 8 + s * 32;
        short8_t u;
#pragma unroll
        for (int j = 0; j < 8; ++j) u[j] = f2bf(Ts[nl][koff + j]);
        *(short8_t*)(out + (size_t)(n0 + nl) * D_MODEL + k0 + koff) = u;
    }
}

// ---------------------------------------------------------------------------
// Kernel 1: QKV GEMM (m97 structure). Q pre-scaled by (1/8)*log2(e) so the
// attention softmax can run in exp2 domain. Q/K and V epilogues round-trip
// through wave-private LDS for coalesced dwordx4 stores.
// ---------------------------------------------------------------------------
__global__ __launch_bounds__(256, 3) void qkv_mfma_gemm_kernel(
    const short* __restrict__ xb,
    const short* __restrict__ wt,
    short* __restrict__ qkv)
{
    const int mBlock = blockIdx.x * 128;
    const int nBlock = blockIdx.y * 128;
    const int which  = blockIdx.z;
    const short* Bt = wt + (size_t)which * W_ELEMS;
    short* outBase  = qkv + (size_t)which * MAT_ELEMS;

    __shared__ short As[128 * 32];               // [m][k] contiguous, 8 KB
    __shared__ short Bs[128 * 32];               // [n][k] contiguous, 8 KB
    __shared__ __align__(16) short Es[4][64 * 72]; // per-wave epilogue, 36 KB

    const int t    = threadIdx.x;
    const int w    = t >> 6;
    const int lane = t & 63;
    const int n16  = lane & 15;
    const int quad = lane >> 4;
    const int mq   = (w & 1) * 64;
    const int nq   = (w >> 1) * 64;

    f32x4 acc[4][4];
#pragma unroll
    for (int i = 0; i < 4; ++i)
#pragma unroll
        for (int j = 0; j < 4; ++j) acc[i][j] = (f32x4){0.f, 0.f, 0.f, 0.f};

    const int off0 = w * 2048 + lane * 16;       // bytes
    const int off1 = off0 + 1024;
    const int r0s = off0 >> 6, k0s = (off0 & 63) >> 1;
    const int r1s = off1 >> 6, k1s = (off1 & 63) >> 1;
    const short* gA0 = xb + (size_t)(mBlock + r0s) * D_MODEL + k0s;
    const short* gA1 = xb + (size_t)(mBlock + r1s) * D_MODEL + k1s;
    const short* gB0 = Bt + (size_t)(nBlock + r0s) * D_MODEL + k0s;
    const short* gB1 = Bt + (size_t)(nBlock + r1s) * D_MODEL + k1s;
    short* lA0 = As + w * 1024;
    short* lA1 = As + w * 1024 + 512;
    short* lB0 = Bs + w * 1024;
    short* lB1 = Bs + w * 1024 + 512;

    for (int k0 = 0; k0 < D_MODEL; k0 += 32) {
        __syncthreads();
        GLD_LDS16(gA0 + k0, lA0);
        GLD_LDS16(gA1 + k0, lA1);
        GLD_LDS16(gB0 + k0, lB0);
        GLD_LDS16(gB1 + k0, lB1);
        __syncthreads();

        short8_t af[4], bf[4];
#pragma unroll
        for (int mt = 0; mt < 4; ++mt)
            af[mt] = *(const short8_t*)&As[(mq + mt * 16 + n16) * 32 + quad * 8];
#pragma unroll
        for (int nt = 0; nt < 4; ++nt)
            bf[nt] = *(const short8_t*)&Bs[(nq + nt * 16 + n16) * 32 + quad * 8];
#pragma unroll
        for (int mt = 0; mt < 4; ++mt)
#pragma unroll
            for (int nt = 0; nt < 4; ++nt)
                acc[mt][nt] = __builtin_amdgcn_mfma_f32_16x16x32_bf16(
                    af[mt], bf[nt], acc[mt][nt], 0, 0, 0);
    }

    // fold 1/sqrt(DH) AND log2(e) into Q (softmax runs in exp2 domain)
    const float oscale = (which == 0) ? 0.125f * 1.44269504089f : 1.0f;
    short* E = &Es[w][0];
    const int h  = (nBlock + nq) >> 6;           // head: fixed per wave tile
    const int m0 = mBlock + mq;                  // 64-aligned
    const int bb = m0 >> 11, ss0 = m0 & 2047;    // tile never crosses b
    const int rsub = lane >> 3;                  // 0..7
    const int ch   = lane & 7;                   // 0..7 (16B chunk)

    if (which < 2) {
        // ---- stage bf16 tile in wave-private LDS [s_local][dh], pad 72 ----
#pragma unroll
        for (int mt = 0; mt < 4; ++mt)
#pragma unroll
            for (int nt = 0; nt < 4; ++nt) {
                const int dhl = nt * 16 + n16;
#pragma unroll
                for (int reg = 0; reg < 4; ++reg) {
                    const int ml = mt * 16 + quad * 4 + reg;
                    E[ml * 72 + dhl] = f2bf(acc[mt][nt][reg] * oscale);
                }
            }
        // wave-private: no barrier needed; lgkmcnt orders write->read
        short* orow = outBase + ((size_t)(bb * N_HEADS + h) * S_LEN + ss0) * D_HEAD
                      + ch * 8;
#pragma unroll
        for (int it = 0; it < 8; ++it) {
            const int row = it * 8 + rsub;       // s_local
            const short8_t v = *(const short8_t*)&E[row * 72 + ch * 8];
            *(short8_t*)(orow + (size_t)row * D_HEAD) = v;
        }
    } else {
        // ---- V transposed (b,h,dh,s): stage [dh_local][s_local], pad 72 ----
#pragma unroll
        for (int mt = 0; mt < 4; ++mt)
#pragma unroll
            for (int nt = 0; nt < 4; ++nt) {
                const int dhl = nt * 16 + n16;
                const int sl0 = mt * 16 + quad * 4;
                short4_t u;
                u[0] = f2bf(acc[mt][nt][0]); u[1] = f2bf(acc[mt][nt][1]);
                u[2] = f2bf(acc[mt][nt][2]); u[3] = f2bf(acc[mt][nt][3]);
                *(short4_t*)&E[dhl * 72 + sl0] = u;
            }
        // coalesced: 8 lanes x 16B = 128B contiguous in s per dh-row
        short* orow = outBase + ((size_t)(bb * N_HEADS + h) * D_HEAD) * S_LEN
                      + ss0 + ch * 8;
#pragma unroll
        for (int it = 0; it < 8; ++it) {
            const int dhl = it * 8 + rsub;       // dh_local 0..63
            const short8_t v = *(const short8_t*)&E[dhl * 72 + ch * 8];
            *(short8_t*)(orow + (size_t)dhl * S_LEN) = v;
        }
    }
}

// ---------------------------------------------------------------------------
// Kernel 2: causal flash attention via bf16 MFMA, v14.
// = v13 (v7 two-group structure + in-lane P + mfma16 PV) with the mfma16
// expressed as the INTRINSIC instead of raw inline asm. v13's index math is
// provably identical to v11's (which PASSED on HW); the v13 failure is
// attributed to asm codegen (missing hazard nops / operand overlap under
// heavy unroll). Intrinsic lets the compiler own hazards+regalloc.
// PV: P stays in registers ([key=kg*16+quad*4+r][q=n] == mfma16 B-frag),
// V read as 16 b64 (same bytes as 8 b128), Ps LDS round-trip deleted.
// Keeps: staged XOR-swizzled K/V, exp2 softmax, defer-max, setprio, paired
// LPT grid (32 bh x 16 pairs), 512 thr, flash-decoding group merge.
// ---------------------------------------------------------------------------
__global__ __launch_bounds__(512, 4) void attn_mfma_kernel(
    const short* __restrict__ qkv,
    float* __restrict__ out)
{
    const int bh   = blockIdx.x;
    const int pr   = blockIdx.y;          // pair index 0..15
    const int t    = threadIdx.x;         // 0..511
    const int w    = t >> 6;              // 0..7
    const int g    = w >> 2;              // tile-group 0/1
    const int wl   = w & 3;               // wave-in-group 0..3
    const int lane = t & 63;
    const int n    = lane & 15;
    const int quad = lane >> 4;

    const short* Q  = qkv + (size_t)bh * HEAD_ELEMS;
    const short* K  = qkv + MAT_ELEMS + (size_t)bh * HEAD_ELEMS;
    const short* Vt = qkv + 2 * MAT_ELEMS + (size_t)bh * HEAD_ELEMS;  // (dh,s)

    __shared__ __align__(16) short Ks[2][64 * 64];       // per-group K, 16 KB
    __shared__ __align__(16) short Vs[2][64 * 64];       // per-group V, 16 KB
    __shared__ float Ml[2][64];                          // per-group m partial
    __shared__ float Ll[2][64];                          // per-group l partial

    // --- staging: group-wave wl stages rows [16wl,16wl+16) of K and V ---
    const int srow0 = wl * 16 + (lane >> 3);             // inst-0 row
    const int srow1 = srow0 + 8;                         // inst-1 row
    const int sd0 = ((lane & 7) ^ (srow0 & 7)) * 8;      // swizzled src offset
    const int sd1 = ((lane & 7) ^ (srow1 & 7)) * 8;
    const short* gK0 = K + srow0 * 64 + sd0;             // += j0*64 per tile
    const short* gK1 = K + srow1 * 64 + sd1;
    const short* gV0 = Vt + (size_t)srow0 * S_LEN + sd0; // += j0 per tile
    const short* gV1 = Vt + (size_t)srow1 * S_LEN + sd1;
    short* lK0 = &Ks[g][(wl * 16) * 64];
    short* lK1 = &Ks[g][(wl * 16 + 8) * 64];
    short* lV0 = &Vs[g][(wl * 16) * 64];
    short* lV1 = &Vs[g][(wl * 16 + 8) * 64];

    // K frag-read physical chunk offset (shorts): a0 at pcK, a1 at pcK^32
    const int pcK = ((quad ^ (n & 7))) * 8;

    const int bb = bh >> 4;
    const int hh = bh & 15;

    for (int pass = 0; pass < 2; ++pass) {
        const int qb = pass ? (31 - pr) : pr;
        const int r0 = qb * 64 + wl * 16;      // both groups cover same q-rows
        const int qrow = r0 + n;

        const short8_t bq0 = *(const short8_t*)(Q + (size_t)qrow * D_HEAD + quad * 8);
        const short8_t bq1 = *(const short8_t*)(Q + (size_t)qrow * D_HEAD + quad * 8 + 32);

        float m = -__builtin_inff();
        float l = 0.f;
        f32x4 o[4];
#pragma unroll
        for (int f = 0; f < 4; ++f) o[f] = (f32x4){0.f, 0.f, 0.f, 0.f};

        const int nrounds = (qb + 2) >> 1;     // ceil((qb+1)/2)
        for (int rd = 0; rd < nrounds; ++rd) {
            const int tg = rd * 2 + g;         // this group's tile
            const bool have = (tg <= qb);
            const int j0 = tg * 64;

            __syncthreads();                   // prior LDS reads done
            if (have) {
                GLD_LDS16(gK0 + j0 * 64, lK0);
                GLD_LDS16(gK1 + j0 * 64, lK1);
                GLD_LDS16(gV0 + j0, lV0);
                GLD_LDS16(gV1 + j0, lV1);
            }
            __syncthreads();                   // vmcnt drained by barrier

            if (!have) continue;               // idle group still hit barriers

            // ---- S^T = K_tile . Q^T (Q pre-scaled by log2e/8) ----
            f32x4 st[4];
            __builtin_amdgcn_s_setprio(1);
#pragma unroll
            for (int kg = 0; kg < 4; ++kg) {
                const int rbase = (kg * 16 + n) * 64;
                const short8_t a0 = *(const short8_t*)&Ks[g][rbase + pcK];
                const short8_t a1 = *(const short8_t*)&Ks[g][rbase + (pcK ^ 32)];
                f32x4 acc = (f32x4){0.f, 0.f, 0.f, 0.f};
                acc = __builtin_amdgcn_mfma_f32_16x16x32_bf16(a0, bq0, acc, 0, 0, 0);
                acc = __builtin_amdgcn_mfma_f32_16x16x32_bf16(a1, bq1, acc, 0, 0, 0);
                st[kg] = acc;
            }
            __builtin_amdgcn_s_setprio(0);

            // ---- online softmax in exp2 domain (mask only on diagonal) ----
            float p[16];
            float mx = -__builtin_inff();
            if (tg == qb) {
#pragma unroll
                for (int kg = 0; kg < 4; ++kg)
#pragma unroll
                    for (int r = 0; r < 4; ++r) {
                        const int key = j0 + kg * 16 + quad * 4 + r;
                        float s = st[kg][r];
                        s = (key <= qrow) ? s : -__builtin_inff();
                        p[kg * 4 + r] = s;
                        mx = fmaxf(mx, s);
                    }
            } else {
#pragma unroll
                for (int i = 0; i < 16; ++i) {
                    const float s = st[i >> 2][i & 3];
                    p[i] = s;
                    mx = fmaxf(mx, s);
                }
            }
            mx = fmaxf(mx, __shfl_xor(mx, 16));
            mx = fmaxf(mx, __shfl_xor(mx, 32));

            float ls = 0.f;
            if (__all(mx <= m + 8.0f)) {
                // defer-max: keep old m, no rescale. P bounded by 2^8.
#pragma unroll
                for (int i = 0; i < 16; ++i) {
                    p[i] = __builtin_amdgcn_exp2f(p[i] - m);
                    ls += p[i];
                }
                ls += __shfl_xor(ls, 16);
                ls += __shfl_xor(ls, 32);
                l += ls;
            } else {
                const float mnew  = fmaxf(m, mx);
                const float alpha = __builtin_amdgcn_exp2f(m - mnew);
#pragma unroll
                for (int i = 0; i < 16; ++i) {
                    p[i] = __builtin_amdgcn_exp2f(p[i] - mnew);
                    ls += p[i];
                }
                ls += __shfl_xor(ls, 16);
                ls += __shfl_xor(ls, 32);
                l = l * alpha + ls;
                m = mnew;
#pragma unroll
                for (int f = 0; f < 4; ++f) {
                    o[f][0] *= alpha; o[f][1] *= alpha;
                    o[f][2] *= alpha; o[f][3] *= alpha;
                }
            }

            // ---- pack P in-lane: [key=kg*16+quad*4+r][q=n] == mfma16 B-frag ----
            short4_t pf[4];
#pragma unroll
            for (int kg = 0; kg < 4; ++kg) {
                const unsigned int b0 = __builtin_bit_cast(unsigned int, p[kg * 4 + 0]);
                const unsigned int b1 = __builtin_bit_cast(unsigned int, p[kg * 4 + 1]);
                const unsigned int b2 = __builtin_bit_cast(unsigned int, p[kg * 4 + 2]);
                const unsigned int b3 = __builtin_bit_cast(unsigned int, p[kg * 4 + 3]);
                uint2 pk;
                pk.x = (b0 >> 16) | (b1 & 0xffff0000u);
                pk.y = (b2 >> 16) | (b3 & 0xffff0000u);
                pf[kg] = __builtin_bit_cast(short4_t, pk);
            }

            // ---- O^T += V^T_tile . P : 4x mfma16 per dh-group, P in regs ----
            // V A-frag: lane n holds V^T[dh=f*16+n][key=kg*16+quad*4+j], j=0..3
            // logical 16B chunk c = 2kg + (quad>>1), swizzled ^(n&7), +8B when
            // quad odd. (Formula HW-validated in v10/v11.)
            __builtin_amdgcn_s_setprio(1);
#pragma unroll
            for (int f = 0; f < 4; ++f) {
                const int rbase = (f * 16 + n) * 64;
                f32x4 acc = o[f];
#pragma unroll
                for (int kg = 0; kg < 4; ++kg) {
                    const int vph = ((2 * kg + (quad >> 1)) ^ (n & 7)) * 8
                                    + (quad & 1) * 4;
                    const short4_t va = *(const short4_t*)&Vs[g][rbase + vph];
                    acc = mfma16_bf16(va, pf[kg], acc);
                }
                o[f] = acc;
            }
            __builtin_amdgcn_s_setprio(0);
        }

        // ---- merge the two group partials (flash-decoding combine) ----
        __syncthreads();   // all staging-buffer reads done
        // group 0 partial -> Ks area (16 KB f32), group 1 -> Vs area.
        // wave region wl*1024 floats; row n, logical chunk c at pc = c^n.
        {
            float* Og = (float*)(g == 0 ? (void*)Ks : (void*)Vs) + wl * 1024;
#pragma unroll
            for (int f = 0; f < 4; ++f) {
                const int c  = f * 4 + quad;
                const int pc = c ^ n;
                *(f32x4*)&Og[n * 64 + pc * 4] = o[f];   // raw partial (no 1/l)
            }
            if (quad == 0) {
                Ml[g][wl * 16 + n] = m;
                Ll[g][wl * 16 + n] = l;
            }
        }
        __syncthreads();
        // combine + store: thread t handles (row = t>>3, 8-float chunk c8 = t&7)
        {
            const int row = t >> 3;              // 0..63
            const int c8  = t & 7;               // 0..7
            const int wr  = row >> 4;            // owning wave region
            const int nr_ = row & 15;
            const float m0 = Ml[0][row], m1 = Ml[1][row];
            const float l0 = Ll[0][row], l1 = Ll[1][row];
            const float M  = fmaxf(m0, m1);
            const float a0 = __builtin_amdgcn_exp2f(m0 - M);
            const float a1 = __builtin_amdgcn_exp2f(m1 - M);
            const float inv = 1.0f / (l0 * a0 + l1 * a1);
            const float* O0 = (const float*)Ks + wr * 1024;
            const float* O1 = (const float*)Vs + wr * 1024;
            float* op = out + ((size_t)(bb * S_LEN + qb * 64 + row)) * D_MODEL
                        + hh * D_HEAD + c8 * 8;
#pragma unroll
            for (int cc = 0; cc < 2; ++cc) {
                const int c  = c8 * 2 + cc;      // logical chunk 0..15
                const int pc = c ^ nr_;
                const f32x4 x0 = *(const f32x4*)&O0[nr_ * 64 + pc * 4];
                const f32x4 x1 = *(const f32x4*)&O1[nr_ * 64 + pc * 4];
                f32x4 r;
                r[0] = (x0[0] * a0 + x1[0] * a1) * inv;
                r[1] = (x0[1] * a0 + x1[1] * a1) * inv;
                r[2] = (x0[2] * a0 + x1[2] * a1) * inv;
                r[3] = (x0[3] * a0 + x1[3] * a1) * inv;
                *(f32x4*)(op + cc * 4) = r;
            }
        }
        // next pass's first round begins with __syncthreads -> safe to restage
    }
}

// ---------------------------------------------------------------------------
extern "C" void kernel_launch(void* const* d_in, const int* in_sizes, int n_in,
                              void* d_out, int out_size, void* d_ws, size_t ws_size,
                              hipStream_t stream) {
    const float* x  = (const float*)d_in[0];
    const float* Wq = (const float*)d_in[1];
    const float* Wk = (const float*)d_in[2];
    const float* Wv = (const float*)d_in[3];
    float* out = (float*)d_out;

    // workspace: xb (8MB) | wt (6MB) | qkv (24MB) = 38MB
    short* xb  = (short*)d_ws;
    short* wt  = xb + MAT_ELEMS;
    short* qkv = wt + 3 * W_ELEMS;

    convert_x_kernel<<<dim3(MAT_ELEMS / (256 * 8)), 256, 0, stream>>>(x, xb);
    transpose_w_kernel<<<dim3(16, 16, 3), 256, 0, stream>>>(Wq, Wk, Wv, wt);

    qkv_mfma_gemm_kernel<<<dim3(32, 8, 3), 256, 0, stream>>>(xb, wt, qkv);

    attn_mfma_kernel<<<dim3(2 * N_HEADS, 16), 512, 0, stream>>>(qkv, out);
}